// Round 4
// baseline (111.778 us; speedup 1.0000x reference)
//
#include <hip/hip_runtime.h>

// sim[x] = (1/9) * sum_c q[c,x] * boxsum3x3(q)[c,x],  q = p * inv,  inv = 1/||p||_c
// (inv factors make the 9-accumulator S_d form unnecessary once inv is known first.)
// Pass A: inv via direct global streaming (no LDS). Pass B: q staged in LDS,
// separable stencil with full-row register blocking (1 acc/pos). Pass C: output
// transpose via [w][t][q]+rotation slab, 1 ds_read_b128 per output float4.
// out[b, c&1, h, w, c>>1] = p[b,c,h,w] * sim[b,h,w]

#define NTHR 256

__global__ __launch_bounds__(NTHR, 3) void bcim_v4(const float* __restrict__ p,
                                                   float* __restrict__ out) {
    __shared__ float qs[64 * 196];   // q slab [cc][196]; reused as red-slab and slabT
    __shared__ float invL[192];      // rows r0-1..r0+4
    __shared__ float simv[128];

    const int tid = threadIdx.x;
    const int b  = blockIdx.x >> 3;
    const int r0 = (blockIdx.x & 7) << 2;
    const float* __restrict__ pb = p + (size_t)b * 131072;

    // stage mapping
    const int w4 = tid & 7;
    const int cs = tid >> 3;          // 0..31
    // stencil mapping
    const int rS = tid >> 6;          // 0..3 (wave-uniform)
    const int cS = tid & 63;

    // ---------------- issue chunk-0 stage loads ----------------
    float4 s[12];
    #pragma unroll
    for (int row = 0; row < 6; ++row) {
        const int grow = r0 - 1 + row;
        const bool ok = (unsigned)grow < 32u;
        #pragma unroll
        for (int ch = 0; ch < 2; ++ch) {
            const int cg = ch * 32 + cs;
            s[ch * 6 + row] = ok ? *(const float4*)(pb + cg * 1024 + grow * 32 + w4 * 4)
                                 : make_float4(0.f, 0.f, 0.f, 0.f);
        }
    }

    // ---------------- pass A: inv-norms via global streaming ----------------
    if (tid < 192) {
        const int g = tid >> 5, ww = tid & 31;
        const int grow = r0 - 1 + g;
        float n2 = 0.f;
        if ((unsigned)grow < 32u) {
            const float* base = pb + grow * 32 + ww;
            float a0 = 0.f, a1 = 0.f, a2 = 0.f, a3 = 0.f;
            #pragma unroll 8
            for (int c = 0; c < 128; c += 4) {
                const float v0 = base[(c + 0) * 1024];
                const float v1 = base[(c + 1) * 1024];
                const float v2 = base[(c + 2) * 1024];
                const float v3 = base[(c + 3) * 1024];
                a0 = fmaf(v0, v0, a0); a1 = fmaf(v1, v1, a1);
                a2 = fmaf(v2, v2, a2); a3 = fmaf(v3, v3, a3);
            }
            n2 = (a0 + a1) + (a2 + a3);
        }
        invL[tid] = (n2 > 0.f) ? (1.0f / sqrtf(n2)) : 0.f;
    }
    __syncthreads();

    float acc[32];
    #pragma unroll
    for (int i = 0; i < 32; ++i) acc[i] = 0.f;

    // ---------------- Wq chunk 0 ----------------
    #pragma unroll
    for (int row = 0; row < 6; ++row) {
        const float4 iq = *(const float4*)&invL[row * 32 + w4 * 4];
        float4 v0 = s[row], v1 = s[6 + row];
        v0.x *= iq.x; v0.y *= iq.y; v0.z *= iq.z; v0.w *= iq.w;
        v1.x *= iq.x; v1.y *= iq.y; v1.z *= iq.z; v1.w *= iq.w;
        *(float4*)&qs[cs * 196 + row * 32 + w4 * 4] = v0;
        *(float4*)&qs[(32 + cs) * 196 + row * 32 + w4 * 4] = v1;
    }
    // issue chunk-1 loads (overlap ST0)
    #pragma unroll
    for (int row = 0; row < 6; ++row) {
        const int grow = r0 - 1 + row;
        const bool ok = (unsigned)grow < 32u;
        #pragma unroll
        for (int ch = 0; ch < 2; ++ch) {
            const int cg = 64 + ch * 32 + cs;
            s[ch * 6 + row] = ok ? *(const float4*)(pb + cg * 1024 + grow * 32 + w4 * 4)
                                 : make_float4(0.f, 0.f, 0.f, 0.f);
        }
    }
    __syncthreads();

    // ---------------- stencil (macro body used twice) ----------------
    #define STENCIL() do {                                                          \
        float vs[34];                                                               \
        vs[0] = 0.f; vs[33] = 0.f;                                                  \
        const int base_ = cS * 196;                                                 \
        _Pragma("unroll")                                                           \
        for (int j = 0; j < 8; ++j) {                                               \
            const float4 a = *(const float4*)&qs[base_ + (rS + 0) * 32 + j * 4];    \
            const float4 d = *(const float4*)&qs[base_ + (rS + 1) * 32 + j * 4];    \
            const float4 e = *(const float4*)&qs[base_ + (rS + 2) * 32 + j * 4];    \
            vs[1 + j * 4 + 0] = a.x + d.x + e.x;                                    \
            vs[1 + j * 4 + 1] = a.y + d.y + e.y;                                    \
            vs[1 + j * 4 + 2] = a.z + d.z + e.z;                                    \
            vs[1 + j * 4 + 3] = a.w + d.w + e.w;                                    \
        }                                                                           \
        _Pragma("unroll")                                                           \
        for (int j = 0; j < 8; ++j) {                                               \
            const float4 d = *(const float4*)&qs[base_ + (rS + 1) * 32 + j * 4];    \
            acc[j*4+0] = fmaf(d.x, vs[j*4+0] + vs[j*4+1] + vs[j*4+2], acc[j*4+0]);  \
            acc[j*4+1] = fmaf(d.y, vs[j*4+1] + vs[j*4+2] + vs[j*4+3], acc[j*4+1]);  \
            acc[j*4+2] = fmaf(d.z, vs[j*4+2] + vs[j*4+3] + vs[j*4+4], acc[j*4+2]);  \
            acc[j*4+3] = fmaf(d.w, vs[j*4+3] + vs[j*4+4] + vs[j*4+5], acc[j*4+3]);  \
        }                                                                           \
    } while (0)

    STENCIL();          // chunk 0
    __syncthreads();

    // ---------------- Wq chunk 1, prefetch phase-3 row 0 ----------------
    #pragma unroll
    for (int row = 0; row < 6; ++row) {
        const float4 iq = *(const float4*)&invL[row * 32 + w4 * 4];
        float4 v0 = s[row], v1 = s[6 + row];
        v0.x *= iq.x; v0.y *= iq.y; v0.z *= iq.z; v0.w *= iq.w;
        v1.x *= iq.x; v1.y *= iq.y; v1.z *= iq.z; v1.w *= iq.w;
        *(float4*)&qs[cs * 196 + row * 32 + w4 * 4] = v0;
        *(float4*)&qs[(32 + cs) * 196 + row * 32 + w4 * 4] = v1;
    }
    float4 c3[4];
    #pragma unroll
    for (int j = 0; j < 4; ++j) {
        const int flat = j * 256 + tid;
        const int cg = flat >> 3, wq = flat & 7;
        c3[j] = *(const float4*)(pb + cg * 1024 + (r0 + 0) * 32 + wq * 4);
    }
    __syncthreads();

    STENCIL();          // chunk 1
    __syncthreads();

    // ---------------- channel reduction -> sim ----------------
    #pragma unroll
    for (int j = 0; j < 8; ++j) {
        *(float4*)&qs[cS * 196 + rS * 32 + j * 4] =
            make_float4(acc[4 * j], acc[4 * j + 1], acc[4 * j + 2], acc[4 * j + 3]);
    }
    __syncthreads();
    if (tid < 128) {
        const int rw = (tid >> 5) * 32 + (tid & 31);
        float t0 = 0.f, t1 = 0.f, t2 = 0.f, t3 = 0.f;
        #pragma unroll 4
        for (int c = 0; c < 64; c += 4) {
            t0 += qs[(c + 0) * 196 + rw]; t1 += qs[(c + 1) * 196 + rw];
            t2 += qs[(c + 2) * 196 + rw]; t3 += qs[(c + 3) * 196 + rw];
        }
        simv[tid] = ((t0 + t1) + (t2 + t3)) * (1.0f / 9.0f);
    }
    __syncthreads();

    // ---------------- phase 3: output transpose via slabT ----------------
    // element (w,t,q) at w*136 + t*68 + ((q + 4*(w>>2) + 8*((q>>2)&3)) & 63)
    float* T = qs;
    for (int h = 0; h < 4; ++h) {
        #pragma unroll
        for (int j = 0; j < 4; ++j) {
            const int flat = j * 256 + tid;
            const int c = flat >> 3, wq = flat & 7;
            const int t = c & 1, q = c >> 1;
            const int o = t * 68 + ((q + 4 * wq + 8 * ((q >> 2) & 3)) & 63);
            T[(wq * 4 + 0) * 136 + o] = c3[j].x;
            T[(wq * 4 + 1) * 136 + o] = c3[j].y;
            T[(wq * 4 + 2) * 136 + o] = c3[j].z;
            T[(wq * 4 + 3) * 136 + o] = c3[j].w;
        }
        __syncthreads();
        if (h < 3) {
            #pragma unroll
            for (int j = 0; j < 4; ++j) {
                const int flat = j * 256 + tid;
                const int cg = flat >> 3, wq = flat & 7;
                c3[j] = *(const float4*)(pb + cg * 1024 + (r0 + h + 1) * 32 + wq * 4);
            }
        }
        #pragma unroll
        for (int j = 0; j < 4; ++j) {
            const int flat = j * 256 + tid;
            const int qq = flat & 15, wr = (flat >> 4) & 31, t = flat >> 9;
            const float sm = simv[h * 32 + wr];
            const float4 v = *(const float4*)
                &T[wr * 136 + t * 68 + ((4 * qq + 4 * (wr >> 2) + 8 * (qq & 3)) & 63)];
            float4 o;
            o.x = v.x * sm; o.y = v.y * sm; o.z = v.z * sm; o.w = v.w * sm;
            *(float4*)(out + (size_t)b * 131072 + (size_t)t * 65536 +
                       (size_t)(r0 + h) * 2048 + wr * 64 + qq * 4) = o;
        }
        __syncthreads();
    }
    #undef STENCIL
}

extern "C" void kernel_launch(void* const* d_in, const int* in_sizes, int n_in,
                              void* d_out, int out_size, void* d_ws, size_t ws_size,
                              hipStream_t stream) {
    const float* p = (const float*)d_in[0];
    float* out = (float*)d_out;
    bcim_v4<<<dim3(2048), dim3(NTHR), 0, stream>>>(p, out);
    (void)in_sizes; (void)n_in; (void)out_size; (void)d_ws; (void)ws_size;
}